// Round 8
// baseline (163.252 us; speedup 1.0000x reference)
//
#include <hip/hip_runtime.h>

#define T_TOKENS 16384
#define DIM 2048
#define NE 8
#define QOUT 2048
#define LSCALE 2.0f

typedef __attribute__((ext_vector_type(4))) float f32x4;
typedef __attribute__((ext_vector_type(8))) short s16x8;
typedef __attribute__((ext_vector_type(4))) short s16x4;

__device__ __forceinline__ short f2bf(float f) {
  unsigned u = __builtin_bit_cast(unsigned, f);
  u += 0x7fffu + ((u >> 16) & 1u);   // round-to-nearest-even
  return (short)(u >> 16);
}

// LDS-only barrier: drains lgkm (ds visibility) but leaves global prefetch
// loads (vmcnt) in flight across the barrier.
__device__ __forceinline__ void barrier_lds() {
  asm volatile("s_waitcnt lgkmcnt(0)" ::: "memory");
  __builtin_amdgcn_s_barrier();
}

// ---------------------------------------------------------------------------
// Pack LoRA weights (f32) into bf16 MFMA-fragment layout.
// lora_a [E][D][R]  -> P1[d8][col=e*16+r][j]  (d = d8*8+j), col in [0,128)
// lora_b [E][R][QO] -> P2[k8][c][j]           (k = k8*8+j = e*16+r)
// ---------------------------------------------------------------------------
__global__ __launch_bounds__(256) void k_pack(
    const float* __restrict__ qa, const float* __restrict__ qb,
    const float* __restrict__ va, const float* __restrict__ vb,
    short* __restrict__ Bq1, short* __restrict__ Bv1,
    short* __restrict__ Bq2, short* __restrict__ Bv2) {
  int tid = blockIdx.x * 256 + threadIdx.x;  // 131072 threads
  if (tid < 65536) {
    int mat = tid >> 15;
    int idx = tid & 32767;          // d8*128 + col
    int d8 = idx >> 7, c = idx & 127;
    int e = c >> 4, r = c & 15;
    const float* src = mat ? va : qa;
    short* dst = mat ? Bv1 : Bq1;
    s16x8 v;
#pragma unroll
    for (int j = 0; j < 8; ++j)
      v[j] = f2bf(src[((size_t)e * DIM + d8 * 8 + j) * 16 + r]);
    *(s16x8*)(dst + (size_t)idx * 8) = v;
  } else {
    int t2 = tid - 65536;
    int mat = t2 >> 15;
    int idx = t2 & 32767;           // k8*2048 + c
    int k8 = idx >> 11, c = idx & 2047;
    const float* src = mat ? vb : qb;
    short* dst = mat ? Bv2 : Bq2;
    s16x8 v;
#pragma unroll
    for (int j = 0; j < 8; ++j)
      v[j] = f2bf(src[(size_t)(k8 * 8 + j) * QOUT + c]);
    *(s16x8*)(dst + (size_t)idx * 8) = v;
  }
}

// ---------------------------------------------------------------------------
// Fully fused: routing + stage1 (low in LDS) + stage2 (direct f32 out).
// Block = 32 tokens, 512 threads (8 waves), grid 512 -> 2 blocks/CU,
// 16 waves/CU (4/SIMD).  LDS = 27 KB (no router-weight staging: rw is read
// from global, L1/L2-hot, wave-coalesced).
//
// Phase A (K=2048, step 64): thread (r=tid>>4, kq=(tid&15)*4) loads one
// distinct float4 of the 32x64 h tile (depth-2 prefetch ring); routing
// logits accumulate f32 vs global rw; tile converted to bf16 in At (dbuf).
// Wave wv owns tokens (wv>>2)*16..+15, stage1-cols (wv&3)*64..+63.
// Phase B (K=128): wave wv owns out-cols wv*512..+511 (wv>>2 = q/v);
// a-frags preloaded from low-LDS; 32 flattened (sub,kk) iters with depth-1
// B2 prefetch; nontemporal f32x4 stores (keeps L2 for B2/rw).
// ---------------------------------------------------------------------------
__global__ __launch_bounds__(512, 4) void k_fused(
    const float* __restrict__ h, const float* __restrict__ rw,
    const short* __restrict__ Bq1, const short* __restrict__ Bv1,
    const short* __restrict__ Bq2, const short* __restrict__ Bv2,
    float* __restrict__ out) {
  __shared__ short At[2][32][72];   // 32 tok x 64 k bf16, 144B rows (9 KB)
  __shared__ short low[32][264];    // 32 tok x 256 cols, 528B rows (16.5 KB)
  __shared__ float wl[32][NE];      // 1 KB

  const int tid = threadIdx.x;
  const int lane = tid & 63, wv = tid >> 6;
  const int lrow = lane & 15, lk = lane >> 4;
  const int row0 = blockIdx.x * 32;
  const int r  = tid >> 4;              // 0..31: token row this thread stages
  const int kq = (tid & 15) * 4;        // k-offset within 64-wide step
  const int tq = wv >> 2, cq = wv & 3;  // phase-A wave tile

  const float* hrow = h + (size_t)(row0 + r) * DIM + kq;
  const short* B1 = (cq >= 2) ? Bv1 : Bq1;
  int cc4[4];
#pragma unroll
  for (int ct = 0; ct < 4; ++ct) cc4[ct] = (cq & 1) * 64 + ct * 16 + lrow;

  // h prefetch ring, depth 2
  float4 hv0 = *(const float4*)(hrow);
  float4 hv1 = *(const float4*)(hrow + 64);

  float lg[NE] = {0.f, 0.f, 0.f, 0.f, 0.f, 0.f, 0.f, 0.f};
  f32x4 acc1[4] = {};

  for (int kb = 0; kb < DIM; kb += 64) {
    const int cur = (kb >> 6) & 1;
    float4 hv2 = *(const float4*)(hrow + ((kb + 128) & (DIM - 1)));  // dead on tails
    // current-step B1 fragments (L2-hot; consumed after the barrier)
    s16x8 bA[4], bB[4];
#pragma unroll
    for (int ct = 0; ct < 4; ++ct) {
      int d8 = (kb >> 3) + lk;
      bA[ct] = *(const s16x8*)(B1 + ((size_t)d8 * 128 + cc4[ct]) * 8);
      bB[ct] = *(const s16x8*)(B1 + ((size_t)(d8 + 4) * 128 + cc4[ct]) * 8);
    }
    // stage A tile (bf16) — independent of rv loads
    s16x4 hb4;
    hb4[0] = f2bf(hv0.x); hb4[1] = f2bf(hv0.y);
    hb4[2] = f2bf(hv0.z); hb4[3] = f2bf(hv0.w);
    *(s16x4*)&At[cur][r][kq] = hb4;
    // routing partials vs global rw (f32-exact)
#pragma unroll
    for (int e = 0; e < NE; ++e) {
      float4 rv = *(const float4*)(rw + e * DIM + kb + kq);
      lg[e] += hv0.x * rv.x + hv0.y * rv.y + hv0.z * rv.z + hv0.w * rv.w;
    }
    barrier_lds();                       // lgkm drain only; vmcnt stays
    s16x8 a0 = *(const s16x8*)&At[cur][tq * 16 + lrow][lk * 8];
    s16x8 a1 = *(const s16x8*)&At[cur][tq * 16 + lrow][32 + lk * 8];
#pragma unroll
    for (int ct = 0; ct < 4; ++ct)
      acc1[ct] = __builtin_amdgcn_mfma_f32_16x16x32_bf16(bA[ct], a0, acc1[ct], 0, 0, 0);
#pragma unroll
    for (int ct = 0; ct < 4; ++ct)
      acc1[ct] = __builtin_amdgcn_mfma_f32_16x16x32_bf16(bB[ct], a1, acc1[ct], 0, 0, 0);
    hv0 = hv1; hv1 = hv2;
  }

  // reduce logits across the 16 k-lanes of each token row
#pragma unroll
  for (int e = 0; e < NE; ++e) {
    lg[e] += __shfl_xor(lg[e], 1, 64);
    lg[e] += __shfl_xor(lg[e], 2, 64);
    lg[e] += __shfl_xor(lg[e], 4, 64);
    lg[e] += __shfl_xor(lg[e], 8, 64);
  }
  // softmax + top-2 (redundant across the 16 lanes of a row; deterministic)
  float mx = lg[0];
#pragma unroll
  for (int e = 1; e < NE; ++e) mx = fmaxf(mx, lg[e]);
  float p[NE], sum = 0.f;
#pragma unroll
  for (int e = 0; e < NE; ++e) { p[e] = expf(lg[e] - mx); sum += p[e]; }
  int i1 = 0; float v1 = p[0];
#pragma unroll
  for (int e = 1; e < NE; ++e) if (p[e] > v1) { v1 = p[e]; i1 = e; }
  float v2 = -1.f; int i2 = 0;
#pragma unroll
  for (int e = 0; e < NE; ++e) if (e != i1 && p[e] > v2) { v2 = p[e]; i2 = e; }
  float s1 = v1 / sum, s2 = v2 / sum;
  float dn = s1 + s2 + 1e-20f;
  float w1 = s1 / dn * LSCALE, w2 = s2 / dn * LSCALE;
  if ((tid & 15) < 8) {
    int el = tid & 7;
    wl[r][el] = (el == i1) ? w1 : ((el == i2) ? w2 : 0.f);
  }

  // issue phase-B prologue loads early (hide under epilogue + barriers)
  const int m = wv >> 2;                  // 0=q, 1=v
  const int cwave = (wv & 3) * 512;       // col group within m
  const short* B2 = m ? Bv2 : Bq2;
  s16x8 bc[4];
#pragma unroll
  for (int ct = 0; ct < 4; ++ct) {
    int c = cwave + ct * 16 + lrow;       // sub=0, kk=0 -> k8 = lk
    bc[ct] = *(const s16x8*)(B2 + ((size_t)lk * QOUT + c) * 8);
  }

  __syncthreads();                        // wl visible
  // scale + write low to LDS (token=lane&15, cols=lk*4+j).
  // Expert for this wave's col tile ct: e = (cq&1)*4 + ct  (cq>=2 is the
  // v matrix, whose experts also index 0..7 — NOT cq*4+ct!)
  float wgt[4];
#pragma unroll
  for (int ct = 0; ct < 4; ++ct) wgt[ct] = wl[tq * 16 + lrow][(cq & 1) * 4 + ct];
#pragma unroll
  for (int ct = 0; ct < 4; ++ct) {
    s16x4 v;
#pragma unroll
    for (int j = 0; j < 4; ++j) v[j] = f2bf(acc1[ct][j] * wgt[ct]);
    *(s16x4*)&low[tq * 16 + lrow][cq * 64 + ct * 16 + lk * 4] = v;
  }
  barrier_lds();                          // low visible

  // -------------------- phase B: out = low @ B2 --------------------
  float* op = out + (size_t)m * T_TOKENS * QOUT;
  s16x8 a2[2][4];
#pragma unroll
  for (int rt = 0; rt < 2; ++rt)
#pragma unroll
    for (int kk = 0; kk < 4; ++kk)
      a2[rt][kk] = *(const s16x8*)&low[rt * 16 + lrow][m * 128 + kk * 32 + lk * 8];

  f32x4 acc[2][4] = {};
#pragma unroll
  for (int it = 0; it < 32; ++it) {
    const int sub = it >> 2, kk = it & 3;
    const int itn = (it + 1) & 31;        // wraps (dead) on last iter
    const int subn = itn >> 2, kkn = itn & 3;
    s16x8 bn[4];
#pragma unroll
    for (int ct = 0; ct < 4; ++ct) {
      int c = cwave + subn * 64 + ct * 16 + lrow;
      bn[ct] = *(const s16x8*)(B2 + ((size_t)(kkn * 4 + lk) * QOUT + c) * 8);
    }
#pragma unroll
    for (int rt = 0; rt < 2; ++rt)
#pragma unroll
      for (int ct = 0; ct < 4; ++ct)
        acc[rt][ct] = __builtin_amdgcn_mfma_f32_16x16x32_bf16(bc[ct], a2[rt][kk], acc[rt][ct], 0, 0, 0);
    if (kk == 3) {
      int cb = cwave + sub * 64;
#pragma unroll
      for (int rt = 0; rt < 2; ++rt)
#pragma unroll
        for (int ct = 0; ct < 4; ++ct) {
          int t = row0 + rt * 16 + lrow;
          int col = cb + ct * 16 + lk * 4;
          __builtin_nontemporal_store(acc[rt][ct], (f32x4*)(op + (size_t)t * QOUT + col));
          acc[rt][ct] = (f32x4){0.f, 0.f, 0.f, 0.f};
        }
    }
#pragma unroll
    for (int ct = 0; ct < 4; ++ct) bc[ct] = bn[ct];
  }
}

extern "C" void kernel_launch(void* const* d_in, const int* in_sizes, int n_in,
                              void* d_out, int out_size, void* d_ws, size_t ws_size,
                              hipStream_t stream) {
  const float* h  = (const float*)d_in[0];
  const float* rw = (const float*)d_in[1];
  const float* qa = (const float*)d_in[2];
  const float* qb = (const float*)d_in[3];
  const float* va = (const float*)d_in[4];
  const float* vb = (const float*)d_in[5];
  float* out = (float*)d_out;
  char* ws = (char*)d_ws;

  short* Bq1 = (short*)(ws);                    // 512 KB each
  short* Bv1 = (short*)(ws + (512 << 10));
  short* Bq2 = (short*)(ws + (1024 << 10));
  short* Bv2 = (short*)(ws + (1536 << 10));

  k_pack<<<512, 256, 0, stream>>>(qa, qb, va, vb, Bq1, Bv1, Bq2, Bv2);
  k_fused<<<T_TOKENS / 32, 512, 0, stream>>>(h, rw, Bq1, Bv1, Bq2, Bv2, out);
}

// Round 9
// 143.251 us; speedup vs baseline: 1.1396x; 1.1396x over previous
//
#include <hip/hip_runtime.h>

#define T_TOKENS 16384
#define DIM 2048
#define NE 8
#define QOUT 2048
#define LSCALE 2.0f

typedef __attribute__((ext_vector_type(4))) float f32x4;
typedef __attribute__((ext_vector_type(8))) short s16x8;
typedef __attribute__((ext_vector_type(4))) short s16x4;

__device__ __forceinline__ short f2bf(float f) {
  unsigned u = __builtin_bit_cast(unsigned, f);
  u += 0x7fffu + ((u >> 16) & 1u);   // round-to-nearest-even
  return (short)(u >> 16);
}

// LDS-only barrier: drains lgkm (ds visibility) but leaves global prefetch
// loads (vmcnt) in flight across the barrier.
__device__ __forceinline__ void barrier_lds() {
  asm volatile("s_waitcnt lgkmcnt(0)" ::: "memory");
  __builtin_amdgcn_s_barrier();
}

// ---------------------------------------------------------------------------
// Pack LoRA weights (f32) into bf16 MFMA-fragment layout.
// lora_a [E][D][R]  -> P1[d8][col=e*16+r][j]  (d = d8*8+j), col in [0,128)
// lora_b [E][R][QO] -> P2[k8][c][j]           (k = k8*8+j = e*16+r)
// ---------------------------------------------------------------------------
__global__ __launch_bounds__(256) void k_pack(
    const float* __restrict__ qa, const float* __restrict__ qb,
    const float* __restrict__ va, const float* __restrict__ vb,
    short* __restrict__ Bq1, short* __restrict__ Bv1,
    short* __restrict__ Bq2, short* __restrict__ Bv2) {
  int tid = blockIdx.x * 256 + threadIdx.x;  // 131072 threads
  if (tid < 65536) {
    int mat = tid >> 15;
    int idx = tid & 32767;          // d8*128 + col
    int d8 = idx >> 7, c = idx & 127;
    int e = c >> 4, r = c & 15;
    const float* src = mat ? va : qa;
    short* dst = mat ? Bv1 : Bq1;
    s16x8 v;
#pragma unroll
    for (int j = 0; j < 8; ++j)
      v[j] = f2bf(src[((size_t)e * DIM + d8 * 8 + j) * 16 + r]);
    *(s16x8*)(dst + (size_t)idx * 8) = v;
  } else {
    int t2 = tid - 65536;
    int mat = t2 >> 15;
    int idx = t2 & 32767;           // k8*2048 + c
    int k8 = idx >> 11, c = idx & 2047;
    const float* src = mat ? vb : qb;
    short* dst = mat ? Bv2 : Bq2;
    s16x8 v;
#pragma unroll
    for (int j = 0; j < 8; ++j)
      v[j] = f2bf(src[(size_t)(k8 * 8 + j) * QOUT + c]);
    *(s16x8*)(dst + (size_t)idx * 8) = v;
  }
}

// ---------------------------------------------------------------------------
// Fully fused: routing + stage1 (low in LDS) + stage2 (direct f32 out).
// Block = 32 tokens, 512 threads (8 waves).  LDS = 27 KB.
// __launch_bounds__(512, 2): empirically the 2nd arg acts like CUDA's
// min-BLOCKS-per-CU on hipcc — (512,4) forced VGPR=64 and catastrophic
// spill (R8 counters: VGPR_Count 64, 210us, all pipes idle).  (512,2)
// gives a >=128 VGPR cap under either interpretation; demand ~110.
//
// Phase A (K=2048, step 64): thread (r=tid>>4, kq=(tid&15)*4) loads one
// distinct float4 of the 32x64 h tile (depth-2 prefetch ring); routing
// logits accumulate f32 vs global rw (L1/L2-hot); tile -> bf16 At (dbuf).
// Wave wv owns tokens (wv>>2)*16..+15, stage1-cols (wv&3)*64..+63.
// Phase B (K=128): wave wv owns out-cols (q/v = wv>>2, group (wv&3)*512);
// a-frags from low-LDS; 32 flattened (sub,kk) iters, depth-1 B2 prefetch;
// nontemporal f32x4 stores.
// ---------------------------------------------------------------------------
__global__ __launch_bounds__(512, 2) void k_fused(
    const float* __restrict__ h, const float* __restrict__ rw,
    const short* __restrict__ Bq1, const short* __restrict__ Bv1,
    const short* __restrict__ Bq2, const short* __restrict__ Bv2,
    float* __restrict__ out) {
  __shared__ short At[2][32][72];   // 32 tok x 64 k bf16, 144B rows (9 KB)
  __shared__ short low[32][264];    // 32 tok x 256 cols, 528B rows (16.5 KB)
  __shared__ float wl[32][NE];      // 1 KB

  const int tid = threadIdx.x;
  const int lane = tid & 63, wv = tid >> 6;
  const int lrow = lane & 15, lk = lane >> 4;
  const int row0 = blockIdx.x * 32;
  const int r  = tid >> 4;              // 0..31: token row this thread stages
  const int kq = (tid & 15) * 4;        // k-offset within 64-wide step
  const int tq = wv >> 2, cq = wv & 3;  // phase-A wave tile

  const float* hrow = h + (size_t)(row0 + r) * DIM + kq;
  const short* B1 = (cq >= 2) ? Bv1 : Bq1;
  int cc4[4];
#pragma unroll
  for (int ct = 0; ct < 4; ++ct) cc4[ct] = (cq & 1) * 64 + ct * 16 + lrow;

  // h prefetch ring, depth 2
  float4 hv0 = *(const float4*)(hrow);
  float4 hv1 = *(const float4*)(hrow + 64);

  float lg[NE] = {0.f, 0.f, 0.f, 0.f, 0.f, 0.f, 0.f, 0.f};
  f32x4 acc1[4] = {};

  for (int kb = 0; kb < DIM; kb += 64) {
    const int cur = (kb >> 6) & 1;
    float4 hv2 = *(const float4*)(hrow + ((kb + 128) & (DIM - 1)));  // dead on tails
    // current-step B1 fragments (L2-hot; consumed after the barrier)
    s16x8 bA[4], bB[4];
#pragma unroll
    for (int ct = 0; ct < 4; ++ct) {
      int d8 = (kb >> 3) + lk;
      bA[ct] = *(const s16x8*)(B1 + ((size_t)d8 * 128 + cc4[ct]) * 8);
      bB[ct] = *(const s16x8*)(B1 + ((size_t)(d8 + 4) * 128 + cc4[ct]) * 8);
    }
    // stage A tile (bf16) — independent of rv loads
    s16x4 hb4;
    hb4[0] = f2bf(hv0.x); hb4[1] = f2bf(hv0.y);
    hb4[2] = f2bf(hv0.z); hb4[3] = f2bf(hv0.w);
    *(s16x4*)&At[cur][r][kq] = hb4;
    // routing partials vs global rw (f32-exact)
#pragma unroll
    for (int e = 0; e < NE; ++e) {
      float4 rv = *(const float4*)(rw + e * DIM + kb + kq);
      lg[e] += hv0.x * rv.x + hv0.y * rv.y + hv0.z * rv.z + hv0.w * rv.w;
    }
    barrier_lds();                       // lgkm drain only; vmcnt stays
    s16x8 a0 = *(const s16x8*)&At[cur][tq * 16 + lrow][lk * 8];
    s16x8 a1 = *(const s16x8*)&At[cur][tq * 16 + lrow][32 + lk * 8];
#pragma unroll
    for (int ct = 0; ct < 4; ++ct)
      acc1[ct] = __builtin_amdgcn_mfma_f32_16x16x32_bf16(bA[ct], a0, acc1[ct], 0, 0, 0);
#pragma unroll
    for (int ct = 0; ct < 4; ++ct)
      acc1[ct] = __builtin_amdgcn_mfma_f32_16x16x32_bf16(bB[ct], a1, acc1[ct], 0, 0, 0);
    hv0 = hv1; hv1 = hv2;
  }

  // reduce logits across the 16 k-lanes of each token row
#pragma unroll
  for (int e = 0; e < NE; ++e) {
    lg[e] += __shfl_xor(lg[e], 1, 64);
    lg[e] += __shfl_xor(lg[e], 2, 64);
    lg[e] += __shfl_xor(lg[e], 4, 64);
    lg[e] += __shfl_xor(lg[e], 8, 64);
  }
  // softmax + top-2 (redundant across the 16 lanes of a row; deterministic)
  float mx = lg[0];
#pragma unroll
  for (int e = 1; e < NE; ++e) mx = fmaxf(mx, lg[e]);
  float p[NE], sum = 0.f;
#pragma unroll
  for (int e = 0; e < NE; ++e) { p[e] = expf(lg[e] - mx); sum += p[e]; }
  int i1 = 0; float v1 = p[0];
#pragma unroll
  for (int e = 1; e < NE; ++e) if (p[e] > v1) { v1 = p[e]; i1 = e; }
  float v2 = -1.f; int i2 = 0;
#pragma unroll
  for (int e = 0; e < NE; ++e) if (e != i1 && p[e] > v2) { v2 = p[e]; i2 = e; }
  float s1 = v1 / sum, s2 = v2 / sum;
  float dn = s1 + s2 + 1e-20f;
  float w1 = s1 / dn * LSCALE, w2 = s2 / dn * LSCALE;
  if ((tid & 15) < 8) {
    int el = tid & 7;
    wl[r][el] = (el == i1) ? w1 : ((el == i2) ? w2 : 0.f);
  }

  // issue phase-B prologue loads early (hide under epilogue + barriers)
  const int m = wv >> 2;                  // 0=q, 1=v
  const int cwave = (wv & 3) * 512;       // col group within m
  const short* B2 = m ? Bv2 : Bq2;
  s16x8 bc[4];
#pragma unroll
  for (int ct = 0; ct < 4; ++ct) {
    int c = cwave + ct * 16 + lrow;       // sub=0, kk=0 -> k8 = lk
    bc[ct] = *(const s16x8*)(B2 + ((size_t)lk * QOUT + c) * 8);
  }

  __syncthreads();                        // wl visible
  // scale + write low to LDS (token=lane&15, cols=lk*4+j).
  // Expert for this wave's col tile ct: e = (cq&1)*4 + ct  (cq>=2 is the
  // v matrix, whose experts also index 0..7 — NOT cq*4+ct!)
  float wgt[4];
#pragma unroll
  for (int ct = 0; ct < 4; ++ct) wgt[ct] = wl[tq * 16 + lrow][(cq & 1) * 4 + ct];
#pragma unroll
  for (int ct = 0; ct < 4; ++ct) {
    s16x4 v;
#pragma unroll
    for (int j = 0; j < 4; ++j) v[j] = f2bf(acc1[ct][j] * wgt[ct]);
    *(s16x4*)&low[tq * 16 + lrow][cq * 64 + ct * 16 + lk * 4] = v;
  }
  barrier_lds();                          // low visible

  // -------------------- phase B: out = low @ B2 --------------------
  float* op = out + (size_t)m * T_TOKENS * QOUT;
  s16x8 a2[2][4];
#pragma unroll
  for (int rt = 0; rt < 2; ++rt)
#pragma unroll
    for (int kk = 0; kk < 4; ++kk)
      a2[rt][kk] = *(const s16x8*)&low[rt * 16 + lrow][m * 128 + kk * 32 + lk * 8];

  f32x4 acc[2][4] = {};
#pragma unroll
  for (int it = 0; it < 32; ++it) {
    const int sub = it >> 2, kk = it & 3;
    const int itn = (it + 1) & 31;        // wraps (dead) on last iter
    const int subn = itn >> 2, kkn = itn & 3;
    s16x8 bn[4];
#pragma unroll
    for (int ct = 0; ct < 4; ++ct) {
      int c = cwave + subn * 64 + ct * 16 + lrow;
      bn[ct] = *(const s16x8*)(B2 + ((size_t)(kkn * 4 + lk) * QOUT + c) * 8);
    }
#pragma unroll
    for (int rt = 0; rt < 2; ++rt)
#pragma unroll
      for (int ct = 0; ct < 4; ++ct)
        acc[rt][ct] = __builtin_amdgcn_mfma_f32_16x16x32_bf16(bc[ct], a2[rt][kk], acc[rt][ct], 0, 0, 0);
    if (kk == 3) {
      int cb = cwave + sub * 64;
#pragma unroll
      for (int rt = 0; rt < 2; ++rt)
#pragma unroll
        for (int ct = 0; ct < 4; ++ct) {
          int t = row0 + rt * 16 + lrow;
          int col = cb + ct * 16 + lk * 4;
          __builtin_nontemporal_store(acc[rt][ct], (f32x4*)(op + (size_t)t * QOUT + col));
          acc[rt][ct] = (f32x4){0.f, 0.f, 0.f, 0.f};
        }
    }
#pragma unroll
    for (int ct = 0; ct < 4; ++ct) bc[ct] = bn[ct];
  }
}

extern "C" void kernel_launch(void* const* d_in, const int* in_sizes, int n_in,
                              void* d_out, int out_size, void* d_ws, size_t ws_size,
                              hipStream_t stream) {
  const float* h  = (const float*)d_in[0];
  const float* rw = (const float*)d_in[1];
  const float* qa = (const float*)d_in[2];
  const float* qb = (const float*)d_in[3];
  const float* va = (const float*)d_in[4];
  const float* vb = (const float*)d_in[5];
  float* out = (float*)d_out;
  char* ws = (char*)d_ws;

  short* Bq1 = (short*)(ws);                    // 512 KB each
  short* Bv1 = (short*)(ws + (512 << 10));
  short* Bq2 = (short*)(ws + (1024 << 10));
  short* Bv2 = (short*)(ws + (1536 << 10));

  k_pack<<<512, 256, 0, stream>>>(qa, qb, va, vb, Bq1, Bv1, Bq2, Bv2);
  k_fused<<<T_TOKENS / 32, 512, 0, stream>>>(h, rw, Bq1, Bv1, Bq2, Bv2, out);
}

// Round 10
// 140.887 us; speedup vs baseline: 1.1587x; 1.0168x over previous
//
#include <hip/hip_runtime.h>

#define T_TOKENS 16384
#define DIM 2048
#define NE 8
#define QOUT 2048
#define LSCALE 2.0f

typedef __attribute__((ext_vector_type(4))) float f32x4;
typedef __attribute__((ext_vector_type(8))) short s16x8;
typedef __attribute__((ext_vector_type(4))) short s16x4;

__device__ __forceinline__ short f2bf(float f) {
  unsigned u = __builtin_bit_cast(unsigned, f);
  u += 0x7fffu + ((u >> 16) & 1u);   // round-to-nearest-even
  return (short)(u >> 16);
}

// LDS-only barrier: drains lgkm (ds visibility) but leaves global prefetch
// loads (vmcnt) in flight across the barrier.
__device__ __forceinline__ void barrier_lds() {
  asm volatile("s_waitcnt lgkmcnt(0)" ::: "memory");
  __builtin_amdgcn_s_barrier();
}

// ---------------------------------------------------------------------------
// Pack LoRA weights (f32) into bf16 MFMA-fragment layout.
// lora_a [E][D][R]  -> P1[d8][col=e*16+r][j]  (d = d8*8+j), col in [0,128)
// lora_b [E][R][QO] -> P2[k8][c][j]           (k = k8*8+j = e*16+r)
// ---------------------------------------------------------------------------
__global__ __launch_bounds__(256) void k_pack(
    const float* __restrict__ qa, const float* __restrict__ qb,
    const float* __restrict__ va, const float* __restrict__ vb,
    short* __restrict__ Bq1, short* __restrict__ Bv1,
    short* __restrict__ Bq2, short* __restrict__ Bv2) {
  int tid = blockIdx.x * 256 + threadIdx.x;  // 131072 threads
  if (tid < 65536) {
    int mat = tid >> 15;
    int idx = tid & 32767;          // d8*128 + col
    int d8 = idx >> 7, c = idx & 127;
    int e = c >> 4, r = c & 15;
    const float* src = mat ? va : qa;
    short* dst = mat ? Bv1 : Bq1;
    s16x8 v;
#pragma unroll
    for (int j = 0; j < 8; ++j)
      v[j] = f2bf(src[((size_t)e * DIM + d8 * 8 + j) * 16 + r]);
    *(s16x8*)(dst + (size_t)idx * 8) = v;
  } else {
    int t2 = tid - 65536;
    int mat = t2 >> 15;
    int idx = t2 & 32767;           // k8*2048 + c
    int k8 = idx >> 11, c = idx & 2047;
    const float* src = mat ? vb : qb;
    short* dst = mat ? Bv2 : Bq2;
    s16x8 v;
#pragma unroll
    for (int j = 0; j < 8; ++j)
      v[j] = f2bf(src[(size_t)(k8 * 8 + j) * QOUT + c]);
    *(s16x8*)(dst + (size_t)idx * 8) = v;
  }
}

// ---------------------------------------------------------------------------
// Fully fused: routing + stage1 (low in LDS) + stage2 (direct f32 out).
// Block = 32 tokens, 512 threads (8 waves).  LDS = 27 KB.
// __launch_bounds__(512) only — R8/R9 showed forcing the 2nd arg caused
// VGPR starvation + spill (VGPR_Count 64, all pipes <27%).
//
// Phase A (K=2048, step 64): thread (r=tid>>4, kq=(tid&15)*4) loads one
// distinct float4 of the 32x64 h tile (depth-2 prefetch ring); routing
// logits accumulate f32 vs global rw (L1-hot: only 2KB unique/step);
// tile -> bf16 At (dbuf).  8-way col split: wave wv owns 32 cols
// (wv*32..+31 of the 256-col concat space) -> all 8 waves load DISTINCT
// B1 fragments (halves L1 traffic vs 4-way split), acc1[2][2], all 32 tok.
// Phase B (K=128): wave wv owns out-cols (q/v = wv>>2, group (wv&3)*512);
// a-frags from low-LDS; rolled loop (#pragma unroll 4, ~1.2KB body) to fit
// I$; depth-1 B2 prefetch; nontemporal f32x4 stores.
// ---------------------------------------------------------------------------
__global__ __launch_bounds__(512) void k_fused(
    const float* __restrict__ h, const float* __restrict__ rw,
    const short* __restrict__ Bq1, const short* __restrict__ Bv1,
    const short* __restrict__ Bq2, const short* __restrict__ Bv2,
    float* __restrict__ out) {
  __shared__ short At[2][32][72];   // 32 tok x 64 k bf16, 144B rows (9 KB)
  __shared__ short low[32][264];    // 32 tok x 256 cols, 528B rows (16.5 KB)
  __shared__ float wl[32][NE];      // 1 KB

  const int tid = threadIdx.x;
  const int lane = tid & 63, wv = tid >> 6;
  const int lrow = lane & 15, lk = lane >> 4;
  const int row0 = blockIdx.x * 32;
  const int r  = tid >> 4;              // 0..31: token row this thread stages
  const int kq = (tid & 15) * 4;        // k-offset within 64-wide step

  const float* hrow = h + (size_t)(row0 + r) * DIM + kq;
  // phase-A: wave wv owns concat cols [wv*32, wv*32+32)
  const short* B1 = (wv >= 4) ? Bv1 : Bq1;
  int cc2[2];
#pragma unroll
  for (int ct = 0; ct < 2; ++ct) cc2[ct] = (wv & 3) * 32 + ct * 16 + lrow;

  // h prefetch ring, depth 2
  float4 hv0 = *(const float4*)(hrow);
  float4 hv1 = *(const float4*)(hrow + 64);

  float lg[NE] = {0.f, 0.f, 0.f, 0.f, 0.f, 0.f, 0.f, 0.f};
  f32x4 acc1[2][2] = {};

#pragma unroll 2
  for (int kb = 0; kb < DIM; kb += 64) {
    const int cur = (kb >> 6) & 1;
    float4 hv2 = *(const float4*)(hrow + ((kb + 128) & (DIM - 1)));  // dead on tails
    // current-step B1 fragments: 4 loads/wave, DISTINCT across waves
    s16x8 bA[2], bB[2];
#pragma unroll
    for (int ct = 0; ct < 2; ++ct) {
      int d8 = (kb >> 3) + lk;
      bA[ct] = *(const s16x8*)(B1 + ((size_t)d8 * 128 + cc2[ct]) * 8);
      bB[ct] = *(const s16x8*)(B1 + ((size_t)(d8 + 4) * 128 + cc2[ct]) * 8);
    }
    // stage A tile (bf16)
    s16x4 hb4;
    hb4[0] = f2bf(hv0.x); hb4[1] = f2bf(hv0.y);
    hb4[2] = f2bf(hv0.z); hb4[3] = f2bf(hv0.w);
    *(s16x4*)&At[cur][r][kq] = hb4;
    // routing partials vs global rw (f32-exact; 2KB unique/step, L1-hot)
#pragma unroll
    for (int e = 0; e < NE; ++e) {
      float4 rv = *(const float4*)(rw + e * DIM + kb + kq);
      lg[e] += hv0.x * rv.x + hv0.y * rv.y + hv0.z * rv.z + hv0.w * rv.w;
    }
    barrier_lds();                       // lgkm drain only; vmcnt stays
    s16x8 a0[2], a1[2];
#pragma unroll
    for (int rt = 0; rt < 2; ++rt) {
      a0[rt] = *(const s16x8*)&At[cur][rt * 16 + lrow][lk * 8];
      a1[rt] = *(const s16x8*)&At[cur][rt * 16 + lrow][32 + lk * 8];
    }
#pragma unroll
    for (int rt = 0; rt < 2; ++rt)
#pragma unroll
      for (int ct = 0; ct < 2; ++ct) {
        acc1[rt][ct] = __builtin_amdgcn_mfma_f32_16x16x32_bf16(bA[ct], a0[rt], acc1[rt][ct], 0, 0, 0);
        acc1[rt][ct] = __builtin_amdgcn_mfma_f32_16x16x32_bf16(bB[ct], a1[rt], acc1[rt][ct], 0, 0, 0);
      }
    hv0 = hv1; hv1 = hv2;
  }

  // reduce logits across the 16 k-lanes of each token row
#pragma unroll
  for (int e = 0; e < NE; ++e) {
    lg[e] += __shfl_xor(lg[e], 1, 64);
    lg[e] += __shfl_xor(lg[e], 2, 64);
    lg[e] += __shfl_xor(lg[e], 4, 64);
    lg[e] += __shfl_xor(lg[e], 8, 64);
  }
  // softmax + top-2 (redundant across the 16 lanes of a row; deterministic)
  float mx = lg[0];
#pragma unroll
  for (int e = 1; e < NE; ++e) mx = fmaxf(mx, lg[e]);
  float p[NE], sum = 0.f;
#pragma unroll
  for (int e = 0; e < NE; ++e) { p[e] = expf(lg[e] - mx); sum += p[e]; }
  int i1 = 0; float v1 = p[0];
#pragma unroll
  for (int e = 1; e < NE; ++e) if (p[e] > v1) { v1 = p[e]; i1 = e; }
  float v2 = -1.f; int i2 = 0;
#pragma unroll
  for (int e = 0; e < NE; ++e) if (e != i1 && p[e] > v2) { v2 = p[e]; i2 = e; }
  float s1 = v1 / sum, s2 = v2 / sum;
  float dn = s1 + s2 + 1e-20f;
  float w1 = s1 / dn * LSCALE, w2 = s2 / dn * LSCALE;
  if ((tid & 15) < 8) {
    int el = tid & 7;
    wl[r][el] = (el == i1) ? w1 : ((el == i2) ? w2 : 0.f);
  }

  // issue phase-B prologue loads early (hide under epilogue + barriers)
  const int m = wv >> 2;                  // 0=q, 1=v
  const int cwave = (wv & 3) * 512;       // col group within m
  const short* B2 = m ? Bv2 : Bq2;
  s16x8 bc[4];
#pragma unroll
  for (int ct = 0; ct < 4; ++ct) {
    int c = cwave + ct * 16 + lrow;       // sub=0, kk=0 -> k8 = lk
    bc[ct] = *(const s16x8*)(B2 + ((size_t)lk * QOUT + c) * 8);
  }

  __syncthreads();                        // wl visible
  // scale + write low to LDS (token=lane&15, cols=lk*4+j).
  // concat col = wv*32 + ct*16 + lk*4+j  ->  e = ((col&127)>>4) = (wv&3)*2+ct
#pragma unroll
  for (int rt = 0; rt < 2; ++rt)
#pragma unroll
    for (int ct = 0; ct < 2; ++ct) {
      int tok = rt * 16 + lrow;
      float wgt = wl[tok][(wv & 3) * 2 + ct];
      s16x4 v;
#pragma unroll
      for (int j = 0; j < 4; ++j) v[j] = f2bf(acc1[rt][ct][j] * wgt);
      *(s16x4*)&low[tok][wv * 32 + ct * 16 + lk * 4] = v;
    }
  barrier_lds();                          // low visible

  // -------------------- phase B: out = low @ B2 --------------------
  float* op = out + (size_t)m * T_TOKENS * QOUT;
  s16x8 a2[2][4];
#pragma unroll
  for (int rt = 0; rt < 2; ++rt)
#pragma unroll
    for (int kk = 0; kk < 4; ++kk)
      a2[rt][kk] = *(const s16x8*)&low[rt * 16 + lrow][m * 128 + kk * 32 + lk * 8];

  f32x4 acc[2][4] = {};
#pragma unroll 4
  for (int it = 0; it < 32; ++it) {
    const int sub = it >> 2, kk = it & 3;  // kk static under unroll 4
    const int itn = (it + 1) & 31;         // wraps (dead) on last iter
    const int subn = itn >> 2, kkn = itn & 3;
    s16x8 bn[4];
#pragma unroll
    for (int ct = 0; ct < 4; ++ct) {
      int c = cwave + subn * 64 + ct * 16 + lrow;
      bn[ct] = *(const s16x8*)(B2 + ((size_t)(kkn * 4 + lk) * QOUT + c) * 8);
    }
#pragma unroll
    for (int rt = 0; rt < 2; ++rt)
#pragma unroll
      for (int ct = 0; ct < 4; ++ct)
        acc[rt][ct] = __builtin_amdgcn_mfma_f32_16x16x32_bf16(bc[ct], a2[rt][kk], acc[rt][ct], 0, 0, 0);
    if (kk == 3) {
      int cb = cwave + sub * 64;
#pragma unroll
      for (int rt = 0; rt < 2; ++rt)
#pragma unroll
        for (int ct = 0; ct < 4; ++ct) {
          int t = row0 + rt * 16 + lrow;
          int col = cb + ct * 16 + lk * 4;
          __builtin_nontemporal_store(acc[rt][ct], (f32x4*)(op + (size_t)t * QOUT + col));
          acc[rt][ct] = (f32x4){0.f, 0.f, 0.f, 0.f};
        }
    }
#pragma unroll
    for (int ct = 0; ct < 4; ++ct) bc[ct] = bn[ct];
  }
}

extern "C" void kernel_launch(void* const* d_in, const int* in_sizes, int n_in,
                              void* d_out, int out_size, void* d_ws, size_t ws_size,
                              hipStream_t stream) {
  const float* h  = (const float*)d_in[0];
  const float* rw = (const float*)d_in[1];
  const float* qa = (const float*)d_in[2];
  const float* qb = (const float*)d_in[3];
  const float* va = (const float*)d_in[4];
  const float* vb = (const float*)d_in[5];
  float* out = (float*)d_out;
  char* ws = (char*)d_ws;

  short* Bq1 = (short*)(ws);                    // 512 KB each
  short* Bv1 = (short*)(ws + (512 << 10));
  short* Bq2 = (short*)(ws + (1024 << 10));
  short* Bv2 = (short*)(ws + (1536 << 10));

  k_pack<<<512, 256, 0, stream>>>(qa, qb, va, vb, Bq1, Bv1, Bq2, Bv2);
  k_fused<<<T_TOKENS / 32, 512, 0, stream>>>(h, rw, Bq1, Bv1, Bq2, Bv2, out);
}